// Round 16
// baseline (322.356 us; speedup 1.0000x reference)
//
#include <hip/hip_runtime.h>

typedef _Float16 f16x8 __attribute__((ext_vector_type(8)));
typedef float    f32x4 __attribute__((ext_vector_type(4)));

#define NROWS  300000
#define NTILES (NROWS/16)      // 18750
#define WPB    8
#define TPB    512
#define NBLK   ((NTILES + WPB - 1) / WPB)  // 2344

// weight-lo plane pre-scaled by 2^11 (stays out of f16-denormal range)
#define LSCALE     2048.0f
#define INV_LSCALE 4.8828125e-4f   // 2^-11 exact

// 16B-aligned rows REQUIRED (RS=140 experiment: odd strides misalign
// ds_read_b128 and cost 2x; bank-spread via stride is dead)
#define RS64   136
#define LO64   72
#define RS128  264
#define LO128  136

// ---- d_ws weight-image offsets (halves); exact R12 values.
#define IMG_P1 0        // FC1@0, FC2@8704
#define IMG_P2 17408    // FC3 cols 0..127
#define IMG_P3 34816    // FC3 cols 128..255
#define IMG_P4 52224    // TP1@0, TP2@8704, TP4@17408
#define IMG_P5 78336    // LIN0
#define IMG_P6 95232    // TP3@0, LIN1@8704

// ---- LDS: double buffer + per-wave bounce (exact R12)
#define BUFSZ  26112
#define OFF_A  0
#define OFF_B  BUFSZ
#define OFF_SBUF (2*BUFSZ)
#define SB_WAVE 1280
#define LDS_HALVES (OFF_SBUF + WPB*SB_WAVE)   // 62464 halves = 124928 B
static_assert(LDS_HALVES * 2 <= 160*1024, "LDS overflow");

struct fp16p { f16x8 h, l; };
struct h2 { _Float16 h, l; };
struct acc2 { f32x4 m, l; };

__device__ __forceinline__ f32x4 MFMA(f16x8 a, f16x8 b, f32x4 c) {
  return __builtin_amdgcn_mfma_f32_16x16x32_f16(a, b, c, 0, 0, 0);
}

__device__ __forceinline__ void gemm2(const fp16p& A0, const fp16p& B0,
                                      const fp16p& A1, const fp16p& B1, acc2& c) {
  c.m = MFMA(A0.h, B0.h, c.m);
  c.m = MFMA(A0.l, B0.h, c.m);
  c.l = MFMA(A0.h, B0.l, c.l);
  c.m = MFMA(A1.h, B1.h, c.m);
  c.m = MFMA(A1.l, B1.h, c.m);
  c.l = MFMA(A1.h, B1.l, c.l);
}
__device__ __forceinline__ f32x4 fin(const acc2& c) { return c.m + c.l * INV_LSCALE; }

__device__ __forceinline__ fp16p bfragp(const _Float16* w, int RS, int LO,
                                        int nt, int ks, int lane) {
  const _Float16* base = w + (nt*16 + (lane & 15))*RS + ks*32 + (lane >> 4)*8;
  fp16p r;
  r.h = *(const f16x8*)base;
  r.l = *(const f16x8*)(base + LO);
  return r;
}

__device__ __forceinline__ h2 split1(float v) {
  h2 r;
  r.h = (_Float16)v;
  r.l = (_Float16)(v - (float)r.h);
  return r;
}

__device__ __forceinline__ fp16p split8(const float* p) {
  f32x4 a = *(const f32x4*)p, b = *(const f32x4*)(p + 4);
  fp16p r;
#pragma unroll
  for (int i = 0; i < 4; ++i) {
    h2 t0 = split1(a[i]);
    h2 t1 = split1(b[i]);
    r.h[i]   = t0.h; r.l[i]   = t0.l;
    r.h[4+i] = t1.h; r.l[4+i] = t1.l;
  }
  return r;
}

__device__ __forceinline__ void load24(const float* p, float* vv) {
#pragma unroll
  for (int i = 0; i < 6; ++i) {
    f32x4 t = *(const f32x4*)(p + 4*i);
    vv[4*i+0] = t[0]; vv[4*i+1] = t[1]; vv[4*i+2] = t[2]; vv[4*i+3] = t[3];
  }
}

// async copy of a 1KB-granular weight image into LDS (wave-striped)
__device__ __forceinline__ void copyimg(_Float16* ldsdst, const _Float16* gsrc,
                                        int nch, int wave, int lane) {
  for (int c = wave; c < nch; c += WPB)
    __builtin_amdgcn_global_load_lds(
        (const __attribute__((address_space(1))) void*)(gsrc + c*512 + lane*8),
        (__attribute__((address_space(3))) void*)(ldsdst + c*512), 16, 0, 0);
}

// ---------- prep kernel: exact R12 ----------
__global__ __launch_bounds__(256) void prep_w(
    const float* __restrict__ Wtp1, const float* __restrict__ Wtp2,
    const float* __restrict__ Wtp3, const float* __restrict__ Wtp4,
    const float* __restrict__ Wfc1, const float* __restrict__ Wfc2,
    const float* __restrict__ Wfc3, const float* __restrict__ Wlin0,
    const float* __restrict__ Wlin1, _Float16* __restrict__ ws)
{
  int e = blockIdx.x*256 + threadIdx.x;   // 0..57343
  const float INV8 = 0.125f, INVS3 = 0.57735026918962576f, INVSMD = 0.08838834764831845f;
  const float* W; int u, n; _Float16* dst; int RS, LOo; float sc;
  if (e < 4096)       { int l = e;        u=l>>6; n=l&63;  W=Wfc1 +u*64+n;  dst=ws+IMG_P1;       RS=RS64;  LOo=LO64;  sc=INV8; }
  else if (e < 8192)  { int l = e-4096;   u=l>>6; n=l&63;  W=Wfc2 +u*64+n;  dst=ws+IMG_P1+8704;  RS=RS64;  LOo=LO64;  sc=INV8; }
  else if (e < 24576) { int l = e-8192;   u=l>>8; n=l&255; W=Wfc3 +u*256+n; RS=RS64; LOo=LO64; sc=INV8;
                        if (n < 128) dst = ws+IMG_P2; else { dst = ws+IMG_P3; n -= 128; } }
  else if (e < 28672) { int l = e-24576;  u=l>>6; n=l&63;  W=Wtp1 +u*64+n;  dst=ws+IMG_P4;       RS=RS64;  LOo=LO64;  sc=INV8; }
  else if (e < 32768) { int l = e-28672;  u=l>>6; n=l&63;  W=Wtp2 +u*64+n;  dst=ws+IMG_P4+8704;  RS=RS64;  LOo=LO64;  sc=INV8; }
  else if (e < 36864) { int l = e-32768;  u=l>>6; n=l&63;  W=Wtp4 +u*64+n;  dst=ws+IMG_P4+17408; RS=RS64;  LOo=LO64;  sc=INV8*INVS3; }
  else if (e < 45056) { int l = e-36864;  u=l>>6; n=l&63;  W=Wlin0+u*64+n;  dst=ws+IMG_P5;       RS=RS128; LOo=LO128; sc=INVSMD; }
  else if (e < 49152) { int l = e-45056;  u=l>>6; n=l&63;  W=Wtp3 +u*64+n;  dst=ws+IMG_P6;       RS=RS64;  LOo=LO64;  sc=INV8; }
  else                { int l = e-49152;  u=l>>6; n=l&63;  W=Wlin1+u*64+n;  dst=ws+IMG_P6+8704;  RS=RS128; LOo=LO128; sc=INVSMD; }
  float v = (*W) * sc;
  _Float16 h = (_Float16)v;
  float res = (v - (float)h) * LSCALE;
  dst[n*RS + u]       = h;
  dst[n*RS + LOo + u] = (_Float16)res;
}

// bound 2: bound-4 proven to corrupt numerics via register pressure (R9 vs R10).
__global__ __launch_bounds__(TPB, 2) void tp_fused(
    const float* __restrict__ x,    const float* __restrict__ y,
    const float* __restrict__ sc,
    const _Float16* __restrict__ wsrc, float* __restrict__ out)
{
  __shared__ _Float16 lds[LDS_HALVES];
  const int tid = threadIdx.x;
  const int lane = tid & 63;
  const int wave = tid >> 6;
  const int tile = blockIdx.x * WPB + wave;
  const bool active = (tile < NTILES);
  const int r0   = (active ? tile : 0) * 16;
  const int arow = lane & 15;
  const int kgrp = lane >> 4;
  const int rowg = r0 + arow;
  _Float16* bufA = lds + OFF_A;
  _Float16* bufB = lds + OFF_B;
  _Float16* swbh = lds + OFF_SBUF + wave*SB_WAVE;
  _Float16* swbl = swbh + 640;

  // ---------- P1 copy (startup) ----------
  copyimg(bufA, wsrc + IMG_P1, 34, wave, lane);

  // ---- y broadcast (overlaps P1 copy) ----
  const float yv = y[r0*4 + lane];
  const float y0A  = __shfl(yv, arow*4 + 0);
  const float y1A0 = __shfl(yv, arow*4 + 1);
  const float y1A1 = __shfl(yv, arow*4 + 2);
  const float y1A2 = __shfl(yv, arow*4 + 3);
  float y0D[4];     // y0 at D-rows (kgrp*4+r) — for post-GEMM y0-commute scaling
  float y1D[3][4];
#pragma unroll
  for (int r = 0; r < 4; ++r)
    y0D[r] = __shfl(yv, (kgrp*4 + r)*4 + 0);
#pragma unroll
  for (int m = 0; m < 3; ++m)
#pragma unroll
    for (int r = 0; r < 4; ++r)
      y1D[m][r] = __shfl(yv, (kgrp*4 + r)*4 + 1 + m);

  // bounce: store row' = r*4+kgrp (bank-spread), read at sigma(arow)
  const int rbase = ((arow & 3)*4 + (arow >> 2))*40;
  auto bounce = [&](const f32x4* zz, bool do_silu, fp16p& A0, fp16p& A1) {
#pragma unroll
    for (int c = 0; c < 2; ++c) {
      asm volatile("s_waitcnt lgkmcnt(0)" ::: "memory");  // WAR
#pragma unroll
      for (int ntl = 0; ntl < 2; ++ntl)
#pragma unroll
        for (int r = 0; r < 4; ++r) {
          float v = zz[c*2 + ntl][r];
          if (do_silu) v = v / (1.f + __expf(-v));
          h2 t = split1(v);
          int o = (r*4 + kgrp)*40 + ntl*16 + arow;
          swbh[o] = t.h;
          swbl[o] = t.l;
        }
      asm volatile("s_waitcnt lgkmcnt(0)" ::: "memory");  // writes visible
      fp16p& A = c ? A1 : A0;
      A.h = *(const f16x8*)(swbh + rbase + kgrp*8);
      A.l = *(const f16x8*)(swbl + rbase + kgrp*8);
    }
  };

  const float* scp = sc + rowg*64;
  fp16p A0 = split8(scp + kgrp*8);
  fp16p A1 = split8(scp + 32 + kgrp*8);

  __syncthreads();                                   // P1 ready
  copyimg(bufB, wsrc + IMG_P2, 34, wave, lane);      // P2 under MLP

  // ================= MLP (FC1@A, FC2@A+8704) =================
  f32x4 z[4];
#pragma unroll
  for (int nt = 0; nt < 4; ++nt) {
    acc2 c{};
    gemm2(A0, bfragp(bufA, RS64, LO64, nt, 0, lane),
          A1, bfragp(bufA, RS64, LO64, nt, 1, lane), c);
    z[nt] = fin(c);
  }
  bounce(z, true, A0, A1);

  f32x4 z2[4];
#pragma unroll
  for (int nt = 0; nt < 4; ++nt) {
    acc2 c{};
    gemm2(A0, bfragp(bufA + 8704, RS64, LO64, nt, 0, lane),
          A1, bfragp(bufA + 8704, RS64, LO64, nt, 1, lane), c);
    z2[nt] = fin(c);
  }
  bounce(z2, true, A0, A1);

  __syncthreads();                                   // A free, P2 arrived
  copyimg(bufA, wsrc + IMG_P3, 34, wave, lane);      // P3 under FC3h1

  f32x4 w[16];   // w[0..7]=w0 cols 0..127, w[8..15]=w1 cols 128..255
#pragma unroll
  for (int nt = 0; nt < 8; ++nt) {
    acc2 c{};
    gemm2(A0, bfragp(bufB, RS64, LO64, nt, 0, lane),
          A1, bfragp(bufB, RS64, LO64, nt, 1, lane), c);
    w[nt] = fin(c);
  }

  __syncthreads();                                   // B free, P3 arrived
  copyimg(bufB, wsrc + IMG_P4, 51, wave, lane);      // P4 under FC3h2

#pragma unroll
  for (int nt = 0; nt < 8; ++nt) {
    acc2 c{};
    gemm2(A0, bfragp(bufA, RS64, LO64, nt, 0, lane),
          A1, bfragp(bufA, RS64, LO64, nt, 1, lane), c);
    w[8 + nt] = fin(c);
  }

  __syncthreads();                                   // A free, P4 arrived
  copyimg(bufA, wsrc + IMG_P5, 33, wave, lane);      // P5 under TP phase

  // ================= x-dependent GEMMs (TP1@B, TP2@B+8704, TP4@B+17408) ======
  // y0-commute: mid0a = y0 ⊙ (x0@TP1) — same A-frags (X0,X1) feed both GEMMs,
  // y0 applied post-GEMM in f32 (exact; removes one f16 quantization site).
  const float* xr = x + rowg*256;
  fp16p X0 = split8(xr + kgrp*8);
  fp16p X1 = split8(xr + 32 + kgrp*8);

  f32x4 t4[4];
  f32x4 m0[8];
#pragma unroll
  for (int nt = 0; nt < 4; ++nt) {
    acc2 ct{}, cm{};
    gemm2(X0, bfragp(bufB + 8704, RS64, LO64, nt, 0, lane),
          X1, bfragp(bufB + 8704, RS64, LO64, nt, 1, lane), ct);
    gemm2(X0, bfragp(bufB, RS64, LO64, nt, 0, lane),
          X1, bfragp(bufB, RS64, LO64, nt, 1, lane), cm);
    t4[nt] = fin(ct);
    f32x4 mm = fin(cm);
#pragma unroll
    for (int r = 0; r < 4; ++r)
      m0[nt][r] = mm[r] * y0D[r];
  }

  fp16p B40, B41;
  {
    float vv[24];
    load24(xr + 64 + 3*(kgrp*8), vv);
#pragma unroll
    for (int j = 0; j < 8; ++j) {
      h2 t = split1(vv[3*j]*y1A0 + vv[3*j+1]*y1A1 + vv[3*j+2]*y1A2);
      B40.h[j] = t.h; B40.l[j] = t.l;
    }
    load24(xr + 64 + 3*(32 + kgrp*8), vv);
#pragma unroll
    for (int j = 0; j < 8; ++j) {
      h2 t = split1(vv[3*j]*y1A0 + vv[3*j+1]*y1A1 + vv[3*j+2]*y1A2);
      B41.h[j] = t.h; B41.l[j] = t.l;
    }
  }
#pragma unroll
  for (int nt = 0; nt < 4; ++nt) {
    acc2 c{};
    gemm2(B40, bfragp(bufB + 17408, RS64, LO64, nt, 0, lane),
          B41, bfragp(bufB + 17408, RS64, LO64, nt, 1, lane), c);
    m0[4+nt] = fin(c);
  }

  __syncthreads();                                   // B free, P5 arrived
  copyimg(bufB, wsrc + IMG_P6, 50, wave, lane);      // P6 under out0

  // ---- out0 = (mid0*w0) @ Wlin0 (LIN0@A) ----
  acc2 o0c[4] = {};
#pragma unroll
  for (int half = 0; half < 2; ++half) {
    f32x4 s[4];
#pragma unroll
    for (int nt = 0; nt < 4; ++nt)
#pragma unroll
      for (int r = 0; r < 4; ++r)
        s[nt][r] = m0[half*4 + nt][r] * w[half*4 + nt][r];
    fp16p S0, S1;
    bounce(s, false, S0, S1);
#pragma unroll
    for (int nt = 0; nt < 4; ++nt)
      gemm2(S0, bfragp(bufA, RS128, LO128, nt, half*2+0, lane),
            S1, bfragp(bufA, RS128, LO128, nt, half*2+1, lane), o0c[nt]);
  }
  if (active) {
#pragma unroll
    for (int nt = 0; nt < 4; ++nt) {
      f32x4 v = fin(o0c[nt]);
#pragma unroll
      for (int r = 0; r < 4; ++r)
        out[(r0 + kgrp*4 + r)*256 + nt*16 + arow] = v[r];
    }
  }

  __syncthreads();                                   // P6 arrived

  // ---- hoisted x1 data for G + m-loop (o0c freed -> register headroom) ----
  float xv0[24], xv1[24];
  load24(xr + 64 + 3*(kgrp*8), xv0);
  load24(xr + 64 + 3*(32 + kgrp*8), xv1);

  // ---- G-hoist: out1 half0 is row-rank-1 in m.  G = (t4 .* w1a) @ LIN1_k01 ----
  f32x4 Gv[4];
  {
    f32x4 s[4];
#pragma unroll
    for (int nt = 0; nt < 4; ++nt)
#pragma unroll
      for (int r = 0; r < 4; ++r)
        s[nt][r] = t4[nt][r] * w[8 + nt][r];
    fp16p S0, S1;
    bounce(s, false, S0, S1);
#pragma unroll
    for (int nt = 0; nt < 4; ++nt) {
      acc2 c{};
      gemm2(S0, bfragp(bufB + 8704, RS128, LO128, nt, 0, lane),
            S1, bfragp(bufB + 8704, RS128, LO128, nt, 1, lane), c);
      Gv[nt] = fin(c);
    }
  }

  // ---- per-m: mb = y0 ⊙ (x1_m@TP3);  out1_m = y1[m]*G + (mb .* w1b)@LIN1_k23 ----
  f32x4 o1f[3][4];
#pragma unroll
  for (int m = 0; m < 3; ++m) {
    fp16p C0, C1;
#pragma unroll
    for (int j = 0; j < 8; ++j) {
      h2 t = split1(xv0[3*j + m]);
      C0.h[j] = t.h; C0.l[j] = t.l;
      h2 u = split1(xv1[3*j + m]);
      C1.h[j] = u.h; C1.l[j] = u.l;
    }
    f32x4 mb[4];
#pragma unroll
    for (int nt = 0; nt < 4; ++nt) {
      acc2 c{};
      gemm2(C0, bfragp(bufB, RS64, LO64, nt, 0, lane),
            C1, bfragp(bufB, RS64, LO64, nt, 1, lane), c);
      f32x4 mv = fin(c);
#pragma unroll
      for (int r = 0; r < 4; ++r)
        mb[nt][r] = mv[r] * y0D[r];
    }

    acc2 o1c[4] = {};
    {
      f32x4 s[4];
#pragma unroll
      for (int nt = 0; nt < 4; ++nt)
#pragma unroll
        for (int r = 0; r < 4; ++r)
          s[nt][r] = mb[nt][r] * w[12 + nt][r];
      fp16p S0, S1;
      bounce(s, false, S0, S1);
#pragma unroll
      for (int nt = 0; nt < 4; ++nt)
        gemm2(S0, bfragp(bufB + 8704, RS128, LO128, nt, 2, lane),
              S1, bfragp(bufB + 8704, RS128, LO128, nt, 3, lane), o1c[nt]);
    }
#pragma unroll
    for (int nt = 0; nt < 4; ++nt) {
      f32x4 h1 = fin(o1c[nt]);
#pragma unroll
      for (int r = 0; r < 4; ++r)
        o1f[m][nt][r] = y1D[m][r] * Gv[nt][r] + h1[r];
    }
  }

  if (active) {
#pragma unroll
    for (int nt = 0; nt < 4; ++nt)
#pragma unroll
      for (int r = 0; r < 4; ++r) {
        float* p = out + (r0 + kgrp*4 + r)*256 + 64 + (nt*16 + arow)*3;
        p[0] = o1f[0][nt][r];
        p[1] = o1f[1][nt][r];
        p[2] = o1f[2][nt][r];
      }
  }
}

extern "C" void kernel_launch(void* const* d_in, const int* in_sizes, int n_in,
                              void* d_out, int out_size, void* d_ws, size_t ws_size,
                              hipStream_t stream) {
  (void)in_sizes; (void)n_in; (void)out_size; (void)ws_size;
  _Float16* ws = (_Float16*)d_ws;
  prep_w<<<224, 256, 0, stream>>>(
      (const float*)d_in[3],  (const float*)d_in[4],  (const float*)d_in[5],
      (const float*)d_in[6],  (const float*)d_in[7],  (const float*)d_in[8],
      (const float*)d_in[9],  (const float*)d_in[10], (const float*)d_in[11], ws);
  tp_fused<<<NBLK, TPB, 0, stream>>>(
      (const float*)d_in[0],  (const float*)d_in[1],  (const float*)d_in[2],
      ws, (float*)d_out);
}

// Round 17
// 312.449 us; speedup vs baseline: 1.0317x; 1.0317x over previous
//
#include <hip/hip_runtime.h>

typedef _Float16 f16x8 __attribute__((ext_vector_type(8)));
typedef float    f32x4 __attribute__((ext_vector_type(4)));

#define NROWS  300000
#define NTILES (NROWS/16)      // 18750
#define WPB    8
#define TPB    512
#define NBLK   ((NTILES + WPB - 1) / WPB)  // 2344

// weight-lo plane pre-scaled by 2^11 (stays out of f16-denormal range)
#define LSCALE     2048.0f
#define INV_LSCALE 4.8828125e-4f   // 2^-11 exact

// 16B-aligned rows REQUIRED (RS=140 experiment: odd strides misalign
// ds_read_b128 and cost 2x; bank-spread via stride is dead)
#define RS64   136
#define LO64   72
#define RS128  264
#define LO128  136

// ---- d_ws weight-image offsets (halves); exact R12 values.
#define IMG_P1 0        // FC1@0, FC2@8704
#define IMG_P2 17408    // FC3 cols 0..127
#define IMG_P3 34816    // FC3 cols 128..255
#define IMG_P4 52224    // TP1@0, TP2@8704, TP4@17408
#define IMG_P5 78336    // LIN0
#define IMG_P6 95232    // TP3@0, LIN1@8704

// ---- LDS: double buffer + per-wave bounce (exact R12)
#define BUFSZ  26112
#define OFF_A  0
#define OFF_B  BUFSZ
#define OFF_SBUF (2*BUFSZ)
#define SB_WAVE 1280
#define LDS_HALVES (OFF_SBUF + WPB*SB_WAVE)   // 62464 halves = 124928 B
static_assert(LDS_HALVES * 2 <= 160*1024, "LDS overflow");

struct fp16p { f16x8 h, l; };
struct h2 { _Float16 h, l; };
struct acc2 { f32x4 m, l; };

__device__ __forceinline__ f32x4 MFMA(f16x8 a, f16x8 b, f32x4 c) {
  return __builtin_amdgcn_mfma_f32_16x16x32_f16(a, b, c, 0, 0, 0);
}

// emulated-fp32 GEMM tile; setprio(1) keeps the matrix pipe fed while other
// waves on the SIMD run their bounce/store phases (T5 — independent-chain regime)
__device__ __forceinline__ void gemm2(const fp16p& A0, const fp16p& B0,
                                      const fp16p& A1, const fp16p& B1, acc2& c) {
  __builtin_amdgcn_s_setprio(1);
  c.m = MFMA(A0.h, B0.h, c.m);
  c.m = MFMA(A0.l, B0.h, c.m);
  c.l = MFMA(A0.h, B0.l, c.l);
  c.m = MFMA(A1.h, B1.h, c.m);
  c.m = MFMA(A1.l, B1.h, c.m);
  c.l = MFMA(A1.h, B1.l, c.l);
  __builtin_amdgcn_s_setprio(0);
}
__device__ __forceinline__ f32x4 fin(const acc2& c) { return c.m + c.l * INV_LSCALE; }

__device__ __forceinline__ fp16p bfragp(const _Float16* w, int RS, int LO,
                                        int nt, int ks, int lane) {
  const _Float16* base = w + (nt*16 + (lane & 15))*RS + ks*32 + (lane >> 4)*8;
  fp16p r;
  r.h = *(const f16x8*)base;
  r.l = *(const f16x8*)(base + LO);
  return r;
}

__device__ __forceinline__ h2 split1(float v) {
  h2 r;
  r.h = (_Float16)v;
  r.l = (_Float16)(v - (float)r.h);
  return r;
}

__device__ __forceinline__ fp16p split8(const float* p) {
  f32x4 a = *(const f32x4*)p, b = *(const f32x4*)(p + 4);
  fp16p r;
#pragma unroll
  for (int i = 0; i < 4; ++i) {
    h2 t0 = split1(a[i]);
    h2 t1 = split1(b[i]);
    r.h[i]   = t0.h; r.l[i]   = t0.l;
    r.h[4+i] = t1.h; r.l[4+i] = t1.l;
  }
  return r;
}

__device__ __forceinline__ void load24(const float* p, float* vv) {
#pragma unroll
  for (int i = 0; i < 6; ++i) {
    f32x4 t = *(const f32x4*)(p + 4*i);
    vv[4*i+0] = t[0]; vv[4*i+1] = t[1]; vv[4*i+2] = t[2]; vv[4*i+3] = t[3];
  }
}

// async copy of a 1KB-granular weight image into LDS (wave-striped)
__device__ __forceinline__ void copyimg(_Float16* ldsdst, const _Float16* gsrc,
                                        int nch, int wave, int lane) {
  for (int c = wave; c < nch; c += WPB)
    __builtin_amdgcn_global_load_lds(
        (const __attribute__((address_space(1))) void*)(gsrc + c*512 + lane*8),
        (__attribute__((address_space(3))) void*)(ldsdst + c*512), 16, 0, 0);
}

// ---------- prep kernel: exact R12 ----------
__global__ __launch_bounds__(256) void prep_w(
    const float* __restrict__ Wtp1, const float* __restrict__ Wtp2,
    const float* __restrict__ Wtp3, const float* __restrict__ Wtp4,
    const float* __restrict__ Wfc1, const float* __restrict__ Wfc2,
    const float* __restrict__ Wfc3, const float* __restrict__ Wlin0,
    const float* __restrict__ Wlin1, _Float16* __restrict__ ws)
{
  int e = blockIdx.x*256 + threadIdx.x;   // 0..57343
  const float INV8 = 0.125f, INVS3 = 0.57735026918962576f, INVSMD = 0.08838834764831845f;
  const float* W; int u, n; _Float16* dst; int RS, LOo; float sc;
  if (e < 4096)       { int l = e;        u=l>>6; n=l&63;  W=Wfc1 +u*64+n;  dst=ws+IMG_P1;       RS=RS64;  LOo=LO64;  sc=INV8; }
  else if (e < 8192)  { int l = e-4096;   u=l>>6; n=l&63;  W=Wfc2 +u*64+n;  dst=ws+IMG_P1+8704;  RS=RS64;  LOo=LO64;  sc=INV8; }
  else if (e < 24576) { int l = e-8192;   u=l>>8; n=l&255; W=Wfc3 +u*256+n; RS=RS64; LOo=LO64; sc=INV8;
                        if (n < 128) dst = ws+IMG_P2; else { dst = ws+IMG_P3; n -= 128; } }
  else if (e < 28672) { int l = e-24576;  u=l>>6; n=l&63;  W=Wtp1 +u*64+n;  dst=ws+IMG_P4;       RS=RS64;  LOo=LO64;  sc=INV8; }
  else if (e < 32768) { int l = e-28672;  u=l>>6; n=l&63;  W=Wtp2 +u*64+n;  dst=ws+IMG_P4+8704;  RS=RS64;  LOo=LO64;  sc=INV8; }
  else if (e < 36864) { int l = e-32768;  u=l>>6; n=l&63;  W=Wtp4 +u*64+n;  dst=ws+IMG_P4+17408; RS=RS64;  LOo=LO64;  sc=INV8*INVS3; }
  else if (e < 45056) { int l = e-36864;  u=l>>6; n=l&63;  W=Wlin0+u*64+n;  dst=ws+IMG_P5;       RS=RS128; LOo=LO128; sc=INVSMD; }
  else if (e < 49152) { int l = e-45056;  u=l>>6; n=l&63;  W=Wtp3 +u*64+n;  dst=ws+IMG_P6;       RS=RS64;  LOo=LO64;  sc=INV8; }
  else                { int l = e-49152;  u=l>>6; n=l&63;  W=Wlin1+u*64+n;  dst=ws+IMG_P6+8704;  RS=RS128; LOo=LO128; sc=INVSMD; }
  float v = (*W) * sc;
  _Float16 h = (_Float16)v;
  float res = (v - (float)h) * LSCALE;
  dst[n*RS + u]       = h;
  dst[n*RS + LOo + u] = (_Float16)res;
}

// bound 2: bound-4 proven to corrupt numerics via register pressure (R9 vs R10).
__global__ __launch_bounds__(TPB, 2) void tp_fused(
    const float* __restrict__ x,    const float* __restrict__ y,
    const float* __restrict__ sc,
    const _Float16* __restrict__ wsrc, float* __restrict__ out)
{
  __shared__ _Float16 lds[LDS_HALVES];
  const int tid = threadIdx.x;
  const int lane = tid & 63;
  const int wave = tid >> 6;
  const int tile = blockIdx.x * WPB + wave;
  const bool active = (tile < NTILES);
  const int r0   = (active ? tile : 0) * 16;
  const int arow = lane & 15;
  const int kgrp = lane >> 4;
  const int rowg = r0 + arow;
  _Float16* bufA = lds + OFF_A;
  _Float16* bufB = lds + OFF_B;
  _Float16* swbh = lds + OFF_SBUF + wave*SB_WAVE;
  _Float16* swbl = swbh + 640;

  // ---------- P1 copy (startup) ----------
  copyimg(bufA, wsrc + IMG_P1, 34, wave, lane);

  // ---- y broadcast (overlaps P1 copy) ----
  const float yv = y[r0*4 + lane];
  const float y1A0 = __shfl(yv, arow*4 + 1);
  const float y1A1 = __shfl(yv, arow*4 + 2);
  const float y1A2 = __shfl(yv, arow*4 + 3);
  float y0D[4];     // y0 at D-rows (kgrp*4+r) — post-GEMM y0-commute scaling
  float y1D[3][4];
#pragma unroll
  for (int r = 0; r < 4; ++r)
    y0D[r] = __shfl(yv, (kgrp*4 + r)*4 + 0);
#pragma unroll
  for (int m = 0; m < 3; ++m)
#pragma unroll
    for (int r = 0; r < 4; ++r)
      y1D[m][r] = __shfl(yv, (kgrp*4 + r)*4 + 1 + m);

  // bounce: store row' = r*4+kgrp (bank-spread), read at sigma(arow)
  const int rbase = ((arow & 3)*4 + (arow >> 2))*40;
  auto bounce = [&](const f32x4* zz, bool do_silu, fp16p& A0, fp16p& A1) {
#pragma unroll
    for (int c = 0; c < 2; ++c) {
      asm volatile("s_waitcnt lgkmcnt(0)" ::: "memory");  // WAR
#pragma unroll
      for (int ntl = 0; ntl < 2; ++ntl)
#pragma unroll
        for (int r = 0; r < 4; ++r) {
          float v = zz[c*2 + ntl][r];
          if (do_silu) v = v / (1.f + __expf(-v));
          h2 t = split1(v);
          int o = (r*4 + kgrp)*40 + ntl*16 + arow;
          swbh[o] = t.h;
          swbl[o] = t.l;
        }
      asm volatile("s_waitcnt lgkmcnt(0)" ::: "memory");  // writes visible
      fp16p& A = c ? A1 : A0;
      A.h = *(const f16x8*)(swbh + rbase + kgrp*8);
      A.l = *(const f16x8*)(swbl + rbase + kgrp*8);
    }
  };

  const float* scp = sc + rowg*64;
  fp16p A0 = split8(scp + kgrp*8);
  fp16p A1 = split8(scp + 32 + kgrp*8);

  __syncthreads();                                   // P1 ready
  copyimg(bufB, wsrc + IMG_P2, 34, wave, lane);      // P2 under MLP

  // ================= MLP (FC1@A, FC2@A+8704) =================
  f32x4 z[4];
#pragma unroll
  for (int nt = 0; nt < 4; ++nt) {
    acc2 c{};
    gemm2(A0, bfragp(bufA, RS64, LO64, nt, 0, lane),
          A1, bfragp(bufA, RS64, LO64, nt, 1, lane), c);
    z[nt] = fin(c);
  }
  bounce(z, true, A0, A1);

  f32x4 z2[4];
#pragma unroll
  for (int nt = 0; nt < 4; ++nt) {
    acc2 c{};
    gemm2(A0, bfragp(bufA + 8704, RS64, LO64, nt, 0, lane),
          A1, bfragp(bufA + 8704, RS64, LO64, nt, 1, lane), c);
    z2[nt] = fin(c);
  }
  bounce(z2, true, A0, A1);

  __syncthreads();                                   // A free, P2 arrived
  copyimg(bufA, wsrc + IMG_P3, 34, wave, lane);      // P3 under FC3h1

  f32x4 w[16];   // w[0..7]=w0 cols 0..127, w[8..15]=w1 cols 128..255
#pragma unroll
  for (int nt = 0; nt < 8; ++nt) {
    acc2 c{};
    gemm2(A0, bfragp(bufB, RS64, LO64, nt, 0, lane),
          A1, bfragp(bufB, RS64, LO64, nt, 1, lane), c);
    w[nt] = fin(c);
  }

  __syncthreads();                                   // B free, P3 arrived
  copyimg(bufB, wsrc + IMG_P4, 51, wave, lane);      // P4 under FC3h2

#pragma unroll
  for (int nt = 0; nt < 8; ++nt) {
    acc2 c{};
    gemm2(A0, bfragp(bufA, RS64, LO64, nt, 0, lane),
          A1, bfragp(bufA, RS64, LO64, nt, 1, lane), c);
    w[8 + nt] = fin(c);
  }

  __syncthreads();                                   // A free, P4 arrived
  copyimg(bufA, wsrc + IMG_P5, 33, wave, lane);      // P5 under TP phase

  // ================= x-dependent GEMMs (TP1@B, TP2@B+8704, TP4@B+17408) ======
  // y0-commute: mid0a = y0 ⊙ (x0@TP1); y0 applied post-GEMM in f32 (exact).
  const float* xr = x + rowg*256;
  fp16p X0 = split8(xr + kgrp*8);
  fp16p X1 = split8(xr + 32 + kgrp*8);

  f32x4 t4[4];
  f32x4 m0[8];
#pragma unroll
  for (int nt = 0; nt < 4; ++nt) {
    acc2 ct{}, cm{};
    gemm2(X0, bfragp(bufB + 8704, RS64, LO64, nt, 0, lane),
          X1, bfragp(bufB + 8704, RS64, LO64, nt, 1, lane), ct);
    gemm2(X0, bfragp(bufB, RS64, LO64, nt, 0, lane),
          X1, bfragp(bufB, RS64, LO64, nt, 1, lane), cm);
    t4[nt] = fin(ct);
    f32x4 mm = fin(cm);
#pragma unroll
    for (int r = 0; r < 4; ++r)
      m0[nt][r] = mm[r] * y0D[r];
  }

  fp16p B40, B41;
  {
    float vv[24];
    load24(xr + 64 + 3*(kgrp*8), vv);
#pragma unroll
    for (int j = 0; j < 8; ++j) {
      h2 t = split1(vv[3*j]*y1A0 + vv[3*j+1]*y1A1 + vv[3*j+2]*y1A2);
      B40.h[j] = t.h; B40.l[j] = t.l;
    }
    load24(xr + 64 + 3*(32 + kgrp*8), vv);
#pragma unroll
    for (int j = 0; j < 8; ++j) {
      h2 t = split1(vv[3*j]*y1A0 + vv[3*j+1]*y1A1 + vv[3*j+2]*y1A2);
      B41.h[j] = t.h; B41.l[j] = t.l;
    }
  }
#pragma unroll
  for (int nt = 0; nt < 4; ++nt) {
    acc2 c{};
    gemm2(B40, bfragp(bufB + 17408, RS64, LO64, nt, 0, lane),
          B41, bfragp(bufB + 17408, RS64, LO64, nt, 1, lane), c);
    m0[4+nt] = fin(c);
  }

  __syncthreads();                                   // B free, P5 arrived
  copyimg(bufB, wsrc + IMG_P6, 50, wave, lane);      // P6 under out0

  // ---- out0 = (mid0*w0) @ Wlin0 (LIN0@A) ----
  acc2 o0c[4] = {};
#pragma unroll
  for (int half = 0; half < 2; ++half) {
    f32x4 s[4];
#pragma unroll
    for (int nt = 0; nt < 4; ++nt)
#pragma unroll
      for (int r = 0; r < 4; ++r)
        s[nt][r] = m0[half*4 + nt][r] * w[half*4 + nt][r];
    fp16p S0, S1;
    bounce(s, false, S0, S1);
#pragma unroll
    for (int nt = 0; nt < 4; ++nt)
      gemm2(S0, bfragp(bufA, RS128, LO128, nt, half*2+0, lane),
            S1, bfragp(bufA, RS128, LO128, nt, half*2+1, lane), o0c[nt]);
  }
  if (active) {
#pragma unroll
    for (int nt = 0; nt < 4; ++nt) {
      f32x4 v = fin(o0c[nt]);
#pragma unroll
      for (int r = 0; r < 4; ++r)
        out[(r0 + kgrp*4 + r)*256 + nt*16 + arow] = v[r];
    }
  }

  __syncthreads();                                   // P6 arrived

  // ---- hoisted x1 data for G + m-loop ----
  float xv0[24], xv1[24];
  load24(xr + 64 + 3*(kgrp*8), xv0);
  load24(xr + 64 + 3*(32 + kgrp*8), xv1);

  // ---- G-hoist: out1 half0 is row-rank-1 in m.  G = (t4 .* w1a) @ LIN1_k01 ----
  f32x4 Gv[4];
  {
    f32x4 s[4];
#pragma unroll
    for (int nt = 0; nt < 4; ++nt)
#pragma unroll
      for (int r = 0; r < 4; ++r)
        s[nt][r] = t4[nt][r] * w[8 + nt][r];
    fp16p S0, S1;
    bounce(s, false, S0, S1);
#pragma unroll
    for (int nt = 0; nt < 4; ++nt) {
      acc2 c{};
      gemm2(S0, bfragp(bufB + 8704, RS128, LO128, nt, 0, lane),
            S1, bfragp(bufB + 8704, RS128, LO128, nt, 1, lane), c);
      Gv[nt] = fin(c);
    }
  }

  // ---- per-m: mb = y0 ⊙ (x1_m@TP3);  out1_m = y1[m]*G + (mb .* w1b)@LIN1_k23 ----
  f32x4 o1f[3][4];
#pragma unroll
  for (int m = 0; m < 3; ++m) {
    fp16p C0, C1;
#pragma unroll
    for (int j = 0; j < 8; ++j) {
      h2 t = split1(xv0[3*j + m]);
      C0.h[j] = t.h; C0.l[j] = t.l;
      h2 u = split1(xv1[3*j + m]);
      C1.h[j] = u.h; C1.l[j] = u.l;
    }
    f32x4 mb[4];
#pragma unroll
    for (int nt = 0; nt < 4; ++nt) {
      acc2 c{};
      gemm2(C0, bfragp(bufB, RS64, LO64, nt, 0, lane),
            C1, bfragp(bufB, RS64, LO64, nt, 1, lane), c);
      f32x4 mv = fin(c);
#pragma unroll
      for (int r = 0; r < 4; ++r)
        mb[nt][r] = mv[r] * y0D[r];
    }

    acc2 o1c[4] = {};
    {
      f32x4 s[4];
#pragma unroll
      for (int nt = 0; nt < 4; ++nt)
#pragma unroll
        for (int r = 0; r < 4; ++r)
          s[nt][r] = mb[nt][r] * w[12 + nt][r];
      fp16p S0, S1;
      bounce(s, false, S0, S1);
#pragma unroll
      for (int nt = 0; nt < 4; ++nt)
        gemm2(S0, bfragp(bufB + 8704, RS128, LO128, nt, 2, lane),
              S1, bfragp(bufB + 8704, RS128, LO128, nt, 3, lane), o1c[nt]);
    }
#pragma unroll
    for (int nt = 0; nt < 4; ++nt) {
      f32x4 h1 = fin(o1c[nt]);
#pragma unroll
      for (int r = 0; r < 4; ++r)
        o1f[m][nt][r] = y1D[m][r] * Gv[nt][r] + h1[r];
    }
  }

  if (active) {
#pragma unroll
    for (int nt = 0; nt < 4; ++nt)
#pragma unroll
      for (int r = 0; r < 4; ++r) {
        float* p = out + (r0 + kgrp*4 + r)*256 + 64 + (nt*16 + arow)*3;
        p[0] = o1f[0][nt][r];
        p[1] = o1f[1][nt][r];
        p[2] = o1f[2][nt][r];
      }
  }
}

extern "C" void kernel_launch(void* const* d_in, const int* in_sizes, int n_in,
                              void* d_out, int out_size, void* d_ws, size_t ws_size,
                              hipStream_t stream) {
  (void)in_sizes; (void)n_in; (void)out_size; (void)ws_size;
  _Float16* ws = (_Float16*)d_ws;
  prep_w<<<224, 256, 0, stream>>>(
      (const float*)d_in[3],  (const float*)d_in[4],  (const float*)d_in[5],
      (const float*)d_in[6],  (const float*)d_in[7],  (const float*)d_in[8],
      (const float*)d_in[9],  (const float*)d_in[10], (const float*)d_in[11], ws);
  tp_fused<<<NBLK, TPB, 0, stream>>>(
      (const float*)d_in[0],  (const float*)d_in[1],  (const float*)d_in[2],
      ws, (float*)d_out);
}

// Round 19
// 312.319 us; speedup vs baseline: 1.0321x; 1.0004x over previous
//
#include <hip/hip_runtime.h>

typedef _Float16 f16x8 __attribute__((ext_vector_type(8)));
typedef float    f32x4 __attribute__((ext_vector_type(4)));

#define NROWS  300000
#define NTILES (NROWS/16)      // 18750
#define WPB    8
#define TPB    512
#define NBLK   ((NTILES + WPB - 1) / WPB)  // 2344

// weight-lo plane pre-scaled by 2^11 (stays out of f16-denormal range)
#define LSCALE     2048.0f
#define INV_LSCALE 4.8828125e-4f   // 2^-11 exact

// 16B-aligned rows REQUIRED (RS=140 experiment: odd strides misalign
// ds_read_b128 and cost 2x; bank-spread via stride is dead)
#define RS64   136
#define LO64   72
#define RS128  264
#define LO128  136

// ---- d_ws weight-image offsets (halves); exact R12 values.
#define IMG_P1 0        // FC1@0, FC2@8704
#define IMG_P2 17408    // FC3 cols 0..127
#define IMG_P3 34816    // FC3 cols 128..255
#define IMG_P4 52224    // TP1@0, TP2@8704, TP4@17408
#define IMG_P5 78336    // LIN0
#define IMG_P6 95232    // TP3@0, LIN1@8704

// ---- LDS: double buffer + per-wave bounce (exact R12)
#define BUFSZ  26112
#define OFF_A  0
#define OFF_B  BUFSZ
#define OFF_SBUF (2*BUFSZ)
#define SB_WAVE 1280
#define LDS_HALVES (OFF_SBUF + WPB*SB_WAVE)   // 62464 halves = 124928 B
static_assert(LDS_HALVES * 2 <= 160*1024, "LDS overflow");

struct fp16p { f16x8 h, l; };
struct h2 { _Float16 h, l; };
struct acc2 { f32x4 m, l; };

__device__ __forceinline__ f32x4 MFMA(f16x8 a, f16x8 b, f32x4 c) {
  return __builtin_amdgcn_mfma_f32_16x16x32_f16(a, b, c, 0, 0, 0);
}

// emulated-fp32 GEMM tile; setprio(1) keeps the matrix pipe fed while other
// waves on the SIMD run their bounce/store phases (T5 — independent-chain regime)
__device__ __forceinline__ void gemm2(const fp16p& A0, const fp16p& B0,
                                      const fp16p& A1, const fp16p& B1, acc2& c) {
  __builtin_amdgcn_s_setprio(1);
  c.m = MFMA(A0.h, B0.h, c.m);
  c.m = MFMA(A0.l, B0.h, c.m);
  c.l = MFMA(A0.h, B0.l, c.l);
  c.m = MFMA(A1.h, B1.h, c.m);
  c.m = MFMA(A1.l, B1.h, c.m);
  c.l = MFMA(A1.l, B1.l, c.l);
  __builtin_amdgcn_s_setprio(0);
}
__device__ __forceinline__ f32x4 fin(const acc2& c) { return c.m + c.l * INV_LSCALE; }

__device__ __forceinline__ fp16p bfragp(const _Float16* w, int RS, int LO,
                                        int nt, int ks, int lane) {
  const _Float16* base = w + (nt*16 + (lane & 15))*RS + ks*32 + (lane >> 4)*8;
  fp16p r;
  r.h = *(const f16x8*)base;
  r.l = *(const f16x8*)(base + LO);
  return r;
}

__device__ __forceinline__ h2 split1(float v) {
  h2 r;
  r.h = (_Float16)v;
  r.l = (_Float16)(v - (float)r.h);
  return r;
}

__device__ __forceinline__ fp16p split8(const float* p) {
  f32x4 a = *(const f32x4*)p, b = *(const f32x4*)(p + 4);
  fp16p r;
#pragma unroll
  for (int i = 0; i < 4; ++i) {
    h2 t0 = split1(a[i]);
    h2 t1 = split1(b[i]);
    r.h[i]   = t0.h; r.l[i]   = t0.l;
    r.h[4+i] = t1.h; r.l[4+i] = t1.l;
  }
  return r;
}

__device__ __forceinline__ void load24(const float* p, float* vv) {
#pragma unroll
  for (int i = 0; i < 6; ++i) {
    f32x4 t = *(const f32x4*)(p + 4*i);
    vv[4*i+0] = t[0]; vv[4*i+1] = t[1]; vv[4*i+2] = t[2]; vv[4*i+3] = t[3];
  }
}

// async copy of a 1KB-granular weight image into LDS (wave-striped)
__device__ __forceinline__ void copyimg(_Float16* ldsdst, const _Float16* gsrc,
                                        int nch, int wave, int lane) {
  for (int c = wave; c < nch; c += WPB)
    __builtin_amdgcn_global_load_lds(
        (const __attribute__((address_space(1))) void*)(gsrc + c*512 + lane*8),
        (__attribute__((address_space(3))) void*)(ldsdst + c*512), 16, 0, 0);
}

// ---------- prep kernel: exact R12 ----------
__global__ __launch_bounds__(256) void prep_w(
    const float* __restrict__ Wtp1, const float* __restrict__ Wtp2,
    const float* __restrict__ Wtp3, const float* __restrict__ Wtp4,
    const float* __restrict__ Wfc1, const float* __restrict__ Wfc2,
    const float* __restrict__ Wfc3, const float* __restrict__ Wlin0,
    const float* __restrict__ Wlin1, _Float16* __restrict__ ws)
{
  int e = blockIdx.x*256 + threadIdx.x;   // 0..57343
  const float INV8 = 0.125f, INVS3 = 0.57735026918962576f, INVSMD = 0.08838834764831845f;
  const float* W; int u, n; _Float16* dst; int RS, LOo; float sc;
  if (e < 4096)       { int l = e;        u=l>>6; n=l&63;  W=Wfc1 +u*64+n;  dst=ws+IMG_P1;       RS=RS64;  LOo=LO64;  sc=INV8; }
  else if (e < 8192)  { int l = e-4096;   u=l>>6; n=l&63;  W=Wfc2 +u*64+n;  dst=ws+IMG_P1+8704;  RS=RS64;  LOo=LO64;  sc=INV8; }
  else if (e < 24576) { int l = e-8192;   u=l>>8; n=l&255; W=Wfc3 +u*256+n; RS=RS64; LOo=LO64; sc=INV8;
                        if (n < 128) dst = ws+IMG_P2; else { dst = ws+IMG_P3; n -= 128; } }
  else if (e < 28672) { int l = e-24576;  u=l>>6; n=l&63;  W=Wtp1 +u*64+n;  dst=ws+IMG_P4;       RS=RS64;  LOo=LO64;  sc=INV8; }
  else if (e < 32768) { int l = e-28672;  u=l>>6; n=l&63;  W=Wtp2 +u*64+n;  dst=ws+IMG_P4+8704;  RS=RS64;  LOo=LO64;  sc=INV8; }
  else if (e < 36864) { int l = e-32768;  u=l>>6; n=l&63;  W=Wtp4 +u*64+n;  dst=ws+IMG_P4+17408; RS=RS64;  LOo=LO64;  sc=INV8*INVS3; }
  else if (e < 45056) { int l = e-36864;  u=l>>6; n=l&63;  W=Wlin0+u*64+n;  dst=ws+IMG_P5;       RS=RS128; LOo=LO128; sc=INVSMD; }
  else if (e < 49152) { int l = e-45056;  u=l>>6; n=l&63;  W=Wtp3 +u*64+n;  dst=ws+IMG_P6;       RS=RS64;  LOo=LO64;  sc=INV8; }
  else                { int l = e-49152;  u=l>>6; n=l&63;  W=Wlin1+u*64+n;  dst=ws+IMG_P6+8704;  RS=RS128; LOo=LO128; sc=INVSMD; }
  float v = (*W) * sc;
  _Float16 h = (_Float16)v;
  float res = (v - (float)h) * LSCALE;
  dst[n*RS + u]       = h;
  dst[n*RS + LOo + u] = (_Float16)res;
}

// bound 2: bound-4 proven to corrupt numerics via register pressure (R9 vs R10).
__global__ __launch_bounds__(TPB, 2) void tp_fused(
    const float* __restrict__ x,    const float* __restrict__ y,
    const float* __restrict__ sc,
    const _Float16* __restrict__ wsrc, float* __restrict__ out)
{
  __shared__ _Float16 lds[LDS_HALVES];
  const int tid = threadIdx.x;
  const int lane = tid & 63;
  const int wave = tid >> 6;
  const int tile = blockIdx.x * WPB + wave;
  const bool active = (tile < NTILES);
  const int r0   = (active ? tile : 0) * 16;
  const int arow = lane & 15;
  const int kgrp = lane >> 4;
  const int rowg = r0 + arow;
  _Float16* bufA = lds + OFF_A;
  _Float16* bufB = lds + OFF_B;
  _Float16* swbh = lds + OFF_SBUF + wave*SB_WAVE;
  _Float16* swbl = swbh + 640;

  // ---------- P1 copy (startup) ----------
  copyimg(bufA, wsrc + IMG_P1, 34, wave, lane);

  // ---- y broadcast (overlaps P1 copy) ----
  const float yv = y[r0*4 + lane];
  const float y1A0 = __shfl(yv, arow*4 + 1);
  const float y1A1 = __shfl(yv, arow*4 + 2);
  const float y1A2 = __shfl(yv, arow*4 + 3);
  float y0D[4];     // y0 at D-rows (kgrp*4+r) — post-GEMM y0-commute scaling
  float y1D[3][4];
#pragma unroll
  for (int r = 0; r < 4; ++r)
    y0D[r] = __shfl(yv, (kgrp*4 + r)*4 + 0);
#pragma unroll
  for (int m = 0; m < 3; ++m)
#pragma unroll
    for (int r = 0; r < 4; ++r)
      y1D[m][r] = __shfl(yv, (kgrp*4 + r)*4 + 1 + m);

  // bounce: store row' = r*4+kgrp (bank-spread), read at sigma(arow)
  const int rbase = ((arow & 3)*4 + (arow >> 2))*40;
  auto bounce = [&](const f32x4* zz, bool do_silu, fp16p& A0, fp16p& A1) {
#pragma unroll
    for (int c = 0; c < 2; ++c) {
      asm volatile("s_waitcnt lgkmcnt(0)" ::: "memory");  // WAR
#pragma unroll
      for (int ntl = 0; ntl < 2; ++ntl)
#pragma unroll
        for (int r = 0; r < 4; ++r) {
          float v = zz[c*2 + ntl][r];
          if (do_silu) v = v / (1.f + __expf(-v));
          h2 t = split1(v);
          int o = (r*4 + kgrp)*40 + ntl*16 + arow;
          swbh[o] = t.h;
          swbl[o] = t.l;
        }
      asm volatile("s_waitcnt lgkmcnt(0)" ::: "memory");  // writes visible
      fp16p& A = c ? A1 : A0;
      A.h = *(const f16x8*)(swbh + rbase + kgrp*8);
      A.l = *(const f16x8*)(swbl + rbase + kgrp*8);
    }
  };

  const float* scp = sc + rowg*64;
  fp16p A0 = split8(scp + kgrp*8);
  fp16p A1 = split8(scp + 32 + kgrp*8);

  __syncthreads();                                   // P1 ready
  copyimg(bufB, wsrc + IMG_P2, 34, wave, lane);      // P2 under MLP

  // ================= MLP (FC1@A, FC2@A+8704) =================
  f32x4 z[4];
#pragma unroll
  for (int nt = 0; nt < 4; ++nt) {
    acc2 c{};
    gemm2(A0, bfragp(bufA, RS64, LO64, nt, 0, lane),
          A1, bfragp(bufA, RS64, LO64, nt, 1, lane), c);
    z[nt] = fin(c);
  }
  bounce(z, true, A0, A1);

  f32x4 z2[4];
#pragma unroll
  for (int nt = 0; nt < 4; ++nt) {
    acc2 c{};
    gemm2(A0, bfragp(bufA + 8704, RS64, LO64, nt, 0, lane),
          A1, bfragp(bufA + 8704, RS64, LO64, nt, 1, lane), c);
    z2[nt] = fin(c);
  }
  bounce(z2, true, A0, A1);

  __syncthreads();                                   // A free, P2 arrived
  copyimg(bufA, wsrc + IMG_P3, 34, wave, lane);      // P3 under FC3h1

  f32x4 w[16];   // w[0..7]=w0 cols 0..127, w[8..15]=w1 cols 128..255
#pragma unroll
  for (int nt = 0; nt < 8; ++nt) {
    acc2 c{};
    gemm2(A0, bfragp(bufB, RS64, LO64, nt, 0, lane),
          A1, bfragp(bufB, RS64, LO64, nt, 1, lane), c);
    w[nt] = fin(c);
  }

  __syncthreads();                                   // B free, P3 arrived
  copyimg(bufB, wsrc + IMG_P4, 51, wave, lane);      // P4 under FC3h2

#pragma unroll
  for (int nt = 0; nt < 8; ++nt) {
    acc2 c{};
    gemm2(A0, bfragp(bufA, RS64, LO64, nt, 0, lane),
          A1, bfragp(bufA, RS64, LO64, nt, 1, lane), c);
    w[8 + nt] = fin(c);
  }

  __syncthreads();                                   // A free, P4 arrived
  copyimg(bufA, wsrc + IMG_P5, 33, wave, lane);      // P5 under TP phase

  // ================= x-dependent GEMMs (TP1@B, TP2@B+8704, TP4@B+17408) ======
  // y0-commute: mid0a = y0 ⊙ (x0@TP1); y0 applied post-GEMM in f32 (exact).
  const float* xr = x + rowg*256;
  fp16p X0 = split8(xr + kgrp*8);
  fp16p X1 = split8(xr + 32 + kgrp*8);

  f32x4 t4[4];
  f32x4 m0[8];
#pragma unroll
  for (int nt = 0; nt < 4; ++nt) {
    acc2 ct{}, cm{};
    gemm2(X0, bfragp(bufB + 8704, RS64, LO64, nt, 0, lane),
          X1, bfragp(bufB + 8704, RS64, LO64, nt, 1, lane), ct);
    gemm2(X0, bfragp(bufB, RS64, LO64, nt, 0, lane),
          X1, bfragp(bufB, RS64, LO64, nt, 1, lane), cm);
    t4[nt] = fin(ct);
    f32x4 mm = fin(cm);
#pragma unroll
    for (int r = 0; r < 4; ++r)
      m0[nt][r] = mm[r] * y0D[r];
  }

  fp16p B40, B41;
  {
    float vv[24];
    load24(xr + 64 + 3*(kgrp*8), vv);
#pragma unroll
    for (int j = 0; j < 8; ++j) {
      h2 t = split1(vv[3*j]*y1A0 + vv[3*j+1]*y1A1 + vv[3*j+2]*y1A2);
      B40.h[j] = t.h; B40.l[j] = t.l;
    }
    load24(xr + 64 + 3*(32 + kgrp*8), vv);
#pragma unroll
    for (int j = 0; j < 8; ++j) {
      h2 t = split1(vv[3*j]*y1A0 + vv[3*j+1]*y1A1 + vv[3*j+2]*y1A2);
      B41.h[j] = t.h; B41.l[j] = t.l;
    }
  }
#pragma unroll
  for (int nt = 0; nt < 4; ++nt) {
    acc2 c{};
    gemm2(B40, bfragp(bufB + 17408, RS64, LO64, nt, 0, lane),
          B41, bfragp(bufB + 17408, RS64, LO64, nt, 1, lane), c);
    m0[4+nt] = fin(c);
  }

  __syncthreads();                                   // B free, P5 arrived
  copyimg(bufB, wsrc + IMG_P6, 50, wave, lane);      // P6 under out0

  // ---- out0 = (mid0*w0) @ Wlin0 (LIN0@A) ----
  acc2 o0c[4] = {};
#pragma unroll
  for (int half = 0; half < 2; ++half) {
    f32x4 s[4];
#pragma unroll
    for (int nt = 0; nt < 4; ++nt)
#pragma unroll
      for (int r = 0; r < 4; ++r)
        s[nt][r] = m0[half*4 + nt][r] * w[half*4 + nt][r];
    fp16p S0, S1;
    bounce(s, false, S0, S1);
#pragma unroll
    for (int nt = 0; nt < 4; ++nt)
      gemm2(S0, bfragp(bufA, RS128, LO128, nt, half*2+0, lane),
            S1, bfragp(bufA, RS128, LO128, nt, half*2+1, lane), o0c[nt]);
  }
  if (active) {
#pragma unroll
    for (int nt = 0; nt < 4; ++nt) {
      f32x4 v = fin(o0c[nt]);
#pragma unroll
      for (int r = 0; r < 4; ++r)
        out[(r0 + kgrp*4 + r)*256 + nt*16 + arow] = v[r];
    }
  }

  __syncthreads();                                   // P6 arrived

  // ---- hoisted x1 data for G + m-loop ----
  float xv0[24], xv1[24];
  load24(xr + 64 + 3*(kgrp*8), xv0);
  load24(xr + 64 + 3*(32 + kgrp*8), xv1);

  // ---- G-hoist: out1 half0 is row-rank-1 in m.  G = (t4 .* w1a) @ LIN1_k01 ----
  f32x4 Gv[4];
  {
    f32x4 s[4];
#pragma unroll
    for (int nt = 0; nt < 4; ++nt)
#pragma unroll
      for (int r = 0; r < 4; ++r)
        s[nt][r] = t4[nt][r] * w[8 + nt][r];
    fp16p S0, S1;
    bounce(s, false, S0, S1);
#pragma unroll
    for (int nt = 0; nt < 4; ++nt) {
      acc2 c{};
      gemm2(S0, bfragp(bufB + 8704, RS128, LO128, nt, 0, lane),
            S1, bfragp(bufB + 8704, RS128, LO128, nt, 1, lane), c);
      Gv[nt] = fin(c);
    }
  }

  // ---- per-m: mb = y0 ⊙ (x1_m@TP3);  out1_m = y1[m]*G + (mb .* w1b)@LIN1_k23 ----
  f32x4 o1f[3][4];
#pragma unroll
  for (int m = 0; m < 3; ++m) {
    fp16p C0, C1;
#pragma unroll
    for (int j = 0; j < 8; ++j) {
      h2 t = split1(xv0[3*j + m]);
      C0.h[j] = t.h; C0.l[j] = t.l;
      h2 u = split1(xv1[3*j + m]);
      C1.h[j] = u.h; C1.l[j] = u.l;
    }
    f32x4 mb[4];
#pragma unroll
    for (int nt = 0; nt < 4; ++nt) {
      acc2 c{};
      gemm2(C0, bfragp(bufB, RS64, LO64, nt, 0, lane),
            C1, bfragp(bufB, RS64, LO64, nt, 1, lane), c);
      f32x4 mv = fin(c);
#pragma unroll
      for (int r = 0; r < 4; ++r)
        mb[nt][r] = mv[r] * y0D[r];
    }

    acc2 o1c[4] = {};
    {
      f32x4 s[4];
#pragma unroll
      for (int nt = 0; nt < 4; ++nt)
#pragma unroll
        for (int r = 0; r < 4; ++r)
          s[nt][r] = mb[nt][r] * w[12 + nt][r];
      fp16p S0, S1;
      bounce(s, false, S0, S1);
#pragma unroll
      for (int nt = 0; nt < 4; ++nt)
        gemm2(S0, bfragp(bufB + 8704, RS128, LO128, nt, 2, lane),
              S1, bfragp(bufB + 8704, RS128, LO128, nt, 3, lane), o1c[nt]);
    }
#pragma unroll
    for (int nt = 0; nt < 4; ++nt) {
      f32x4 h1 = fin(o1c[nt]);
#pragma unroll
      for (int r = 0; r < 4; ++r)
        o1f[m][nt][r] = y1D[m][r] * Gv[nt][r] + h1[r];
    }
  }

  if (active) {
#pragma unroll
    for (int nt = 0; nt < 4; ++nt)
#pragma unroll
      for (int r = 0; r < 4; ++r) {
        float* p = out + (r0 + kgrp*4 + r)*256 + 64 + (nt*16 + arow)*3;
        p[0] = o1f[0][nt][r];
        p[1] = o1f[1][nt][r];
        p[2] = o1f[2][nt][r];
      }
  }
}

extern "C" void kernel_launch(void* const* d_in, const int* in_sizes, int n_in,
                              void* d_out, int out_size, void* d_ws, size_t ws_size,
                              hipStream_t stream) {
  (void)in_sizes; (void)n_in; (void)out_size; (void)ws_size;
  _Float16* ws = (_Float16*)d_ws;
  prep_w<<<224, 256, 0, stream>>>(
      (const float*)d_in[3],  (const float*)d_in[4],  (const float*)d_in[5],
      (const float*)d_in[6],  (const float*)d_in[7],  (const float*)d_in[8],
      (const float*)d_in[9],  (const float*)d_in[10], (const float*)d_in[11], ws);
  tp_fused<<<NBLK, TPB, 0, stream>>>(
      (const float*)d_in[0],  (const float*)d_in[1],  (const float*)d_in[2],
      ws, (float*)d_out);
}

// Round 20
// 311.545 us; speedup vs baseline: 1.0347x; 1.0025x over previous
//
#include <hip/hip_runtime.h>

typedef _Float16 f16x8 __attribute__((ext_vector_type(8)));
typedef float    f32x4 __attribute__((ext_vector_type(4)));

#define NROWS  300000
#define NTILES (NROWS/16)      // 18750
#define WPB    8
#define TPB    512
#define NBLK   ((NTILES + WPB - 1) / WPB)  // 2344

// weight-lo plane pre-scaled by 2^11 (stays out of f16-denormal range)
#define LSCALE     2048.0f
#define INV_LSCALE 4.8828125e-4f   // 2^-11 exact

// 16B-aligned rows REQUIRED (RS=140 experiment: odd strides misalign
// ds_read_b128 and cost 2x; bank-spread via stride is dead)
#define RS64   136
#define LO64   72
#define RS128  264
#define LO128  136

// ---- d_ws weight-image offsets (halves); exact R12 values.
#define IMG_P1 0        // FC1@0, FC2@8704
#define IMG_P2 17408    // FC3 cols 0..127
#define IMG_P3 34816    // FC3 cols 128..255
#define IMG_P4 52224    // TP1@0, TP2@8704, TP4@17408
#define IMG_P5 78336    // LIN0
#define IMG_P6 95232    // TP3@0, LIN1@8704

// ---- LDS: double buffer + per-wave bounce (exact R12)
#define BUFSZ  26112
#define OFF_A  0
#define OFF_B  BUFSZ
#define OFF_SBUF (2*BUFSZ)
#define SB_WAVE 1280
#define LDS_HALVES (OFF_SBUF + WPB*SB_WAVE)   // 62464 halves = 124928 B
static_assert(LDS_HALVES * 2 <= 160*1024, "LDS overflow");

struct fp16p { f16x8 h, l; };
struct h2 { _Float16 h, l; };
struct acc2 { f32x4 m, l; };

__device__ __forceinline__ f32x4 MFMA(f16x8 a, f16x8 b, f32x4 c) {
  return __builtin_amdgcn_mfma_f32_16x16x32_f16(a, b, c, 0, 0, 0);
}

// emulated-fp32 GEMM tile; setprio(1) keeps the matrix pipe fed (T5).
// NOTE R19 post-mortem: the lo-acc term for the 2nd K-half MUST be A1.h*B1.l
// (weight-lo x act-hi). R18/R19 had a transcription typo (A1.l*B1.l) that
// halved the weight-lo correction and doubled absmax 0.0156->0.0312.
__device__ __forceinline__ void gemm2(const fp16p& A0, const fp16p& B0,
                                      const fp16p& A1, const fp16p& B1, acc2& c) {
  __builtin_amdgcn_s_setprio(1);
  c.m = MFMA(A0.h, B0.h, c.m);
  c.m = MFMA(A0.l, B0.h, c.m);
  c.l = MFMA(A0.h, B0.l, c.l);
  c.m = MFMA(A1.h, B1.h, c.m);
  c.m = MFMA(A1.l, B1.h, c.m);
  c.l = MFMA(A1.h, B1.l, c.l);
  __builtin_amdgcn_s_setprio(0);
}
__device__ __forceinline__ f32x4 fin(const acc2& c) { return c.m + c.l * INV_LSCALE; }

__device__ __forceinline__ fp16p bfragp(const _Float16* w, int RS, int LO,
                                        int nt, int ks, int lane) {
  const _Float16* base = w + (nt*16 + (lane & 15))*RS + ks*32 + (lane >> 4)*8;
  fp16p r;
  r.h = *(const f16x8*)base;
  r.l = *(const f16x8*)(base + LO);
  return r;
}

__device__ __forceinline__ h2 split1(float v) {
  h2 r;
  r.h = (_Float16)v;
  r.l = (_Float16)(v - (float)r.h);
  return r;
}

__device__ __forceinline__ fp16p split8(const float* p) {
  f32x4 a = *(const f32x4*)p, b = *(const f32x4*)(p + 4);
  fp16p r;
#pragma unroll
  for (int i = 0; i < 4; ++i) {
    h2 t0 = split1(a[i]);
    h2 t1 = split1(b[i]);
    r.h[i]   = t0.h; r.l[i]   = t0.l;
    r.h[4+i] = t1.h; r.l[4+i] = t1.l;
  }
  return r;
}

__device__ __forceinline__ void load24(const float* p, float* vv) {
#pragma unroll
  for (int i = 0; i < 6; ++i) {
    f32x4 t = *(const f32x4*)(p + 4*i);
    vv[4*i+0] = t[0]; vv[4*i+1] = t[1]; vv[4*i+2] = t[2]; vv[4*i+3] = t[3];
  }
}

// async copy of a 1KB-granular weight image into LDS (wave-striped)
__device__ __forceinline__ void copyimg(_Float16* ldsdst, const _Float16* gsrc,
                                        int nch, int wave, int lane) {
  for (int c = wave; c < nch; c += WPB)
    __builtin_amdgcn_global_load_lds(
        (const __attribute__((address_space(1))) void*)(gsrc + c*512 + lane*8),
        (__attribute__((address_space(3))) void*)(ldsdst + c*512), 16, 0, 0);
}

// ---------- prep kernel: exact R12 ----------
__global__ __launch_bounds__(256) void prep_w(
    const float* __restrict__ Wtp1, const float* __restrict__ Wtp2,
    const float* __restrict__ Wtp3, const float* __restrict__ Wtp4,
    const float* __restrict__ Wfc1, const float* __restrict__ Wfc2,
    const float* __restrict__ Wfc3, const float* __restrict__ Wlin0,
    const float* __restrict__ Wlin1, _Float16* __restrict__ ws)
{
  int e = blockIdx.x*256 + threadIdx.x;   // 0..57343
  const float INV8 = 0.125f, INVS3 = 0.57735026918962576f, INVSMD = 0.08838834764831845f;
  const float* W; int u, n; _Float16* dst; int RS, LOo; float sc;
  if (e < 4096)       { int l = e;        u=l>>6; n=l&63;  W=Wfc1 +u*64+n;  dst=ws+IMG_P1;       RS=RS64;  LOo=LO64;  sc=INV8; }
  else if (e < 8192)  { int l = e-4096;   u=l>>6; n=l&63;  W=Wfc2 +u*64+n;  dst=ws+IMG_P1+8704;  RS=RS64;  LOo=LO64;  sc=INV8; }
  else if (e < 24576) { int l = e-8192;   u=l>>8; n=l&255; W=Wfc3 +u*256+n; RS=RS64; LOo=LO64; sc=INV8;
                        if (n < 128) dst = ws+IMG_P2; else { dst = ws+IMG_P3; n -= 128; } }
  else if (e < 28672) { int l = e-24576;  u=l>>6; n=l&63;  W=Wtp1 +u*64+n;  dst=ws+IMG_P4;       RS=RS64;  LOo=LO64;  sc=INV8; }
  else if (e < 32768) { int l = e-28672;  u=l>>6; n=l&63;  W=Wtp2 +u*64+n;  dst=ws+IMG_P4+8704;  RS=RS64;  LOo=LO64;  sc=INV8; }
  else if (e < 36864) { int l = e-32768;  u=l>>6; n=l&63;  W=Wtp4 +u*64+n;  dst=ws+IMG_P4+17408; RS=RS64;  LOo=LO64;  sc=INV8*INVS3; }
  else if (e < 45056) { int l = e-36864;  u=l>>6; n=l&63;  W=Wlin0+u*64+n;  dst=ws+IMG_P5;       RS=RS128; LOo=LO128; sc=INVSMD; }
  else if (e < 49152) { int l = e-45056;  u=l>>6; n=l&63;  W=Wtp3 +u*64+n;  dst=ws+IMG_P6;       RS=RS64;  LOo=LO64;  sc=INV8; }
  else                { int l = e-49152;  u=l>>6; n=l&63;  W=Wlin1+u*64+n;  dst=ws+IMG_P6+8704;  RS=RS128; LOo=LO128; sc=INVSMD; }
  float v = (*W) * sc;
  _Float16 h = (_Float16)v;
  float res = (v - (float)h) * LSCALE;
  dst[n*RS + u]       = h;
  dst[n*RS + LOo + u] = (_Float16)res;
}

// bound 2: bound-4 proven to corrupt numerics via register pressure (R9 vs R10).
__global__ __launch_bounds__(TPB, 2) void tp_fused(
    const float* __restrict__ x,    const float* __restrict__ y,
    const float* __restrict__ sc,
    const _Float16* __restrict__ wsrc, float* __restrict__ out)
{
  __shared__ _Float16 lds[LDS_HALVES];
  const int tid = threadIdx.x;
  const int lane = tid & 63;
  const int wave = tid >> 6;
  const int tile = blockIdx.x * WPB + wave;
  const bool active = (tile < NTILES);
  const int r0   = (active ? tile : 0) * 16;
  const int arow = lane & 15;
  const int kgrp = lane >> 4;
  const int rowg = r0 + arow;
  _Float16* bufA = lds + OFF_A;
  _Float16* bufB = lds + OFF_B;
  _Float16* swbh = lds + OFF_SBUF + wave*SB_WAVE;
  _Float16* swbl = swbh + 640;

  // ---------- P1 copy (startup) ----------
  copyimg(bufA, wsrc + IMG_P1, 34, wave, lane);

  // ---- y broadcast (overlaps P1 copy) ----
  const float yv = y[r0*4 + lane];
  const float y1A0 = __shfl(yv, arow*4 + 1);
  const float y1A1 = __shfl(yv, arow*4 + 2);
  const float y1A2 = __shfl(yv, arow*4 + 3);
  float y0D[4];     // y0 at D-rows (kgrp*4+r) — post-GEMM y0-commute scaling
  float y1D[3][4];
#pragma unroll
  for (int r = 0; r < 4; ++r)
    y0D[r] = __shfl(yv, (kgrp*4 + r)*4 + 0);
#pragma unroll
  for (int m = 0; m < 3; ++m)
#pragma unroll
    for (int r = 0; r < 4; ++r)
      y1D[m][r] = __shfl(yv, (kgrp*4 + r)*4 + 1 + m);

  // bounce: store row' = r*4+kgrp (bank-spread), read at sigma(arow)
  const int rbase = ((arow & 3)*4 + (arow >> 2))*40;
  auto bounce = [&](const f32x4* zz, bool do_silu, fp16p& A0, fp16p& A1) {
#pragma unroll
    for (int c = 0; c < 2; ++c) {
      asm volatile("s_waitcnt lgkmcnt(0)" ::: "memory");  // WAR
#pragma unroll
      for (int ntl = 0; ntl < 2; ++ntl)
#pragma unroll
        for (int r = 0; r < 4; ++r) {
          float v = zz[c*2 + ntl][r];
          if (do_silu) v = v / (1.f + __expf(-v));
          h2 t = split1(v);
          int o = (r*4 + kgrp)*40 + ntl*16 + arow;
          swbh[o] = t.h;
          swbl[o] = t.l;
        }
      asm volatile("s_waitcnt lgkmcnt(0)" ::: "memory");  // writes visible
      fp16p& A = c ? A1 : A0;
      A.h = *(const f16x8*)(swbh + rbase + kgrp*8);
      A.l = *(const f16x8*)(swbl + rbase + kgrp*8);
    }
  };

  const float* scp = sc + rowg*64;
  fp16p A0 = split8(scp + kgrp*8);
  fp16p A1 = split8(scp + 32 + kgrp*8);

  __syncthreads();                                   // P1 ready
  copyimg(bufB, wsrc + IMG_P2, 34, wave, lane);      // P2 under MLP

  // ================= MLP (FC1@A, FC2@A+8704) =================
  f32x4 z[4];
#pragma unroll
  for (int nt = 0; nt < 4; ++nt) {
    acc2 c{};
    gemm2(A0, bfragp(bufA, RS64, LO64, nt, 0, lane),
          A1, bfragp(bufA, RS64, LO64, nt, 1, lane), c);
    z[nt] = fin(c);
  }
  bounce(z, true, A0, A1);

  f32x4 z2[4];
#pragma unroll
  for (int nt = 0; nt < 4; ++nt) {
    acc2 c{};
    gemm2(A0, bfragp(bufA + 8704, RS64, LO64, nt, 0, lane),
          A1, bfragp(bufA + 8704, RS64, LO64, nt, 1, lane), c);
    z2[nt] = fin(c);
  }
  bounce(z2, true, A0, A1);

  __syncthreads();                                   // A free, P2 arrived
  copyimg(bufA, wsrc + IMG_P3, 34, wave, lane);      // P3 under FC3h1

  f32x4 w[16];   // w[0..7]=w0 cols 0..127, w[8..15]=w1 cols 128..255
#pragma unroll
  for (int nt = 0; nt < 8; ++nt) {
    acc2 c{};
    gemm2(A0, bfragp(bufB, RS64, LO64, nt, 0, lane),
          A1, bfragp(bufB, RS64, LO64, nt, 1, lane), c);
    w[nt] = fin(c);
  }

  __syncthreads();                                   // B free, P3 arrived
  copyimg(bufB, wsrc + IMG_P4, 51, wave, lane);      // P4 under FC3h2

#pragma unroll
  for (int nt = 0; nt < 8; ++nt) {
    acc2 c{};
    gemm2(A0, bfragp(bufA, RS64, LO64, nt, 0, lane),
          A1, bfragp(bufA, RS64, LO64, nt, 1, lane), c);
    w[8 + nt] = fin(c);
  }

  __syncthreads();                                   // A free, P4 arrived
  copyimg(bufA, wsrc + IMG_P5, 33, wave, lane);      // P5 under TP phase

  // ================= x-dependent GEMMs (TP1@B, TP2@B+8704, TP4@B+17408) ======
  // y0-commute: mid0a = y0 ⊙ (x0@TP1); y0 applied post-GEMM in f32 (exact).
  const float* xr = x + rowg*256;
  fp16p X0 = split8(xr + kgrp*8);
  fp16p X1 = split8(xr + 32 + kgrp*8);

  f32x4 t4[4];
  f32x4 m0[8];
#pragma unroll
  for (int nt = 0; nt < 4; ++nt) {
    acc2 ct{}, cm{};
    gemm2(X0, bfragp(bufB + 8704, RS64, LO64, nt, 0, lane),
          X1, bfragp(bufB + 8704, RS64, LO64, nt, 1, lane), ct);
    gemm2(X0, bfragp(bufB, RS64, LO64, nt, 0, lane),
          X1, bfragp(bufB, RS64, LO64, nt, 1, lane), cm);
    t4[nt] = fin(ct);
    f32x4 mm = fin(cm);
#pragma unroll
    for (int r = 0; r < 4; ++r)
      m0[nt][r] = mm[r] * y0D[r];
  }

  fp16p B40, B41;
  {
    float vv[24];
    load24(xr + 64 + 3*(kgrp*8), vv);
#pragma unroll
    for (int j = 0; j < 8; ++j) {
      h2 t = split1(vv[3*j]*y1A0 + vv[3*j+1]*y1A1 + vv[3*j+2]*y1A2);
      B40.h[j] = t.h; B40.l[j] = t.l;
    }
    load24(xr + 64 + 3*(32 + kgrp*8), vv);
#pragma unroll
    for (int j = 0; j < 8; ++j) {
      h2 t = split1(vv[3*j]*y1A0 + vv[3*j+1]*y1A1 + vv[3*j+2]*y1A2);
      B41.h[j] = t.h; B41.l[j] = t.l;
    }
  }
#pragma unroll
  for (int nt = 0; nt < 4; ++nt) {
    acc2 c{};
    gemm2(B40, bfragp(bufB + 17408, RS64, LO64, nt, 0, lane),
          B41, bfragp(bufB + 17408, RS64, LO64, nt, 1, lane), c);
    m0[4+nt] = fin(c);
  }

  __syncthreads();                                   // B free, P5 arrived
  copyimg(bufB, wsrc + IMG_P6, 50, wave, lane);      // P6 under out0

  // ---- out0 = (mid0*w0) @ Wlin0 (LIN0@A) ----
  acc2 o0c[4] = {};
#pragma unroll
  for (int half = 0; half < 2; ++half) {
    f32x4 s[4];
#pragma unroll
    for (int nt = 0; nt < 4; ++nt)
#pragma unroll
      for (int r = 0; r < 4; ++r)
        s[nt][r] = m0[half*4 + nt][r] * w[half*4 + nt][r];
    fp16p S0, S1;
    bounce(s, false, S0, S1);
#pragma unroll
    for (int nt = 0; nt < 4; ++nt)
      gemm2(S0, bfragp(bufA, RS128, LO128, nt, half*2+0, lane),
            S1, bfragp(bufA, RS128, LO128, nt, half*2+1, lane), o0c[nt]);
  }
  if (active) {
#pragma unroll
    for (int nt = 0; nt < 4; ++nt) {
      f32x4 v = fin(o0c[nt]);
#pragma unroll
      for (int r = 0; r < 4; ++r)
        out[(r0 + kgrp*4 + r)*256 + nt*16 + arow] = v[r];
    }
  }

  __syncthreads();                                   // P6 arrived

  // ---- hoisted x1 data for G + m-loop ----
  float xv0[24], xv1[24];
  load24(xr + 64 + 3*(kgrp*8), xv0);
  load24(xr + 64 + 3*(32 + kgrp*8), xv1);

  // ---- G-hoist: out1 half0 is row-rank-1 in m.  G = (t4 .* w1a) @ LIN1_k01 ----
  f32x4 Gv[4];
  {
    f32x4 s[4];
#pragma unroll
    for (int nt = 0; nt < 4; ++nt)
#pragma unroll
      for (int r = 0; r < 4; ++r)
        s[nt][r] = t4[nt][r] * w[8 + nt][r];
    fp16p S0, S1;
    bounce(s, false, S0, S1);
#pragma unroll
    for (int nt = 0; nt < 4; ++nt) {
      acc2 c{};
      gemm2(S0, bfragp(bufB + 8704, RS128, LO128, nt, 0, lane),
            S1, bfragp(bufB + 8704, RS128, LO128, nt, 1, lane), c);
      Gv[nt] = fin(c);
    }
  }

  // ---- per-m: mb = y0 ⊙ (x1_m@TP3);  out1_m = y1[m]*G + (mb .* w1b)@LIN1_k23 ----
  f32x4 o1f[3][4];
#pragma unroll
  for (int m = 0; m < 3; ++m) {
    fp16p C0, C1;
#pragma unroll
    for (int j = 0; j < 8; ++j) {
      h2 t = split1(xv0[3*j + m]);
      C0.h[j] = t.h; C0.l[j] = t.l;
      h2 u = split1(xv1[3*j + m]);
      C1.h[j] = u.h; C1.l[j] = u.l;
    }
    f32x4 mb[4];
#pragma unroll
    for (int nt = 0; nt < 4; ++nt) {
      acc2 c{};
      gemm2(C0, bfragp(bufB, RS64, LO64, nt, 0, lane),
            C1, bfragp(bufB, RS64, LO64, nt, 1, lane), c);
      f32x4 mv = fin(c);
#pragma unroll
      for (int r = 0; r < 4; ++r)
        mb[nt][r] = mv[r] * y0D[r];
    }

    acc2 o1c[4] = {};
    {
      f32x4 s[4];
#pragma unroll
      for (int nt = 0; nt < 4; ++nt)
#pragma unroll
        for (int r = 0; r < 4; ++r)
          s[nt][r] = mb[nt][r] * w[12 + nt][r];
      fp16p S0, S1;
      bounce(s, false, S0, S1);
#pragma unroll
      for (int nt = 0; nt < 4; ++nt)
        gemm2(S0, bfragp(bufB + 8704, RS128, LO128, nt, 2, lane),
              S1, bfragp(bufB + 8704, RS128, LO128, nt, 3, lane), o1c[nt]);
    }
#pragma unroll
    for (int nt = 0; nt < 4; ++nt) {
      f32x4 h1 = fin(o1c[nt]);
#pragma unroll
      for (int r = 0; r < 4; ++r)
        o1f[m][nt][r] = y1D[m][r] * Gv[nt][r] + h1[r];
    }
  }

  if (active) {
#pragma unroll
    for (int nt = 0; nt < 4; ++nt)
#pragma unroll
      for (int r = 0; r < 4; ++r) {
        float* p = out + (r0 + kgrp*4 + r)*256 + 64 + (nt*16 + arow)*3;
        p[0] = o1f[0][nt][r];
        p[1] = o1f[1][nt][r];
        p[2] = o1f[2][nt][r];
      }
  }
}

extern "C" void kernel_launch(void* const* d_in, const int* in_sizes, int n_in,
                              void* d_out, int out_size, void* d_ws, size_t ws_size,
                              hipStream_t stream) {
  (void)in_sizes; (void)n_in; (void)out_size; (void)ws_size;
  _Float16* ws = (_Float16*)d_ws;
  prep_w<<<224, 256, 0, stream>>>(
      (const float*)d_in[3],  (const float*)d_in[4],  (const float*)d_in[5],
      (const float*)d_in[6],  (const float*)d_in[7],  (const float*)d_in[8],
      (const float*)d_in[9],  (const float*)d_in[10], (const float*)d_in[11], ws);
  tp_fused<<<NBLK, TPB, 0, stream>>>(
      (const float*)d_in[0],  (const float*)d_in[1],  (const float*)d_in[2],
      ws, (float*)d_out);
}